// Round 1
// baseline (20283.354 us; speedup 1.0000x reference)
//
#include <hip/hip_runtime.h>
#include <hip/hip_bf16.h>

// DecoderRNN: 3-layer GRU, B=512, S=200, H=1024, V=100, teacher-forced scan.
// Strategy:
//  - precompute (per call): de=[z|cond], table = emb@wih0[:,:512].T  [100,3072],
//    gprec0 = de@wih0[:,512:].T + bih0  [512,3072], hinit = de@i2h_w.T+i2h_b,
//    logit_de = de@out_w[:,1024:].T + out_b  [512,100], bf16-packed weights.
//  - per step: G0/G1/G2 gates kernels (bf16 MFMA 32x32x16, GRU cell fused in
//    epilogue, in-block 2-way K-split across waves), OUT logits kernel.

typedef __hip_bfloat16 bf16;
typedef __attribute__((ext_vector_type(8))) short short8;
typedef __attribute__((ext_vector_type(8))) unsigned short ushort8;
typedef __attribute__((ext_vector_type(16))) float f32x16;

#define B_ 512
#define S_ 200
#define H_ 1024
#define V_ 100

__device__ __forceinline__ float bf2f(bf16 x) { return __bfloat162float(x); }
__device__ __forceinline__ float us2f(unsigned short u) {
  return __uint_as_float(((unsigned)u) << 16);
}

// ---------------------------------------------------------------------------
// Gates kernel: computes h_l(t) for one layer.
//   gates[b][g*1024+n] = sum_k A[b][k] * Wp[g][n][k]   (A = concat of A0,A1)
// Wp layout: [3][1024][KTOT] bf16 (n-major, k contiguous).
// Waves: w = tid>>6; wm = w&1 (M-half of 64-row tile), ks = w>>1 (K-half).
// For KTOT=2048 the K midpoint == wih|whh boundary, so ks=0's N-accum is the
// complete i_n and ks=1's is the complete h_n. For layer 0 (KTOT=1024, whh
// only) both halves sum into h_n and i_n comes from table+gprec0 gather.
// Epilogue (ks==0 waves): GRU cell -> h_out bf16.
// LDS granules (16B) XOR-swizzled: granule (row, kcs) holds k-chunk
// kc = kcs ^ (row&7)  -> conflict-free ds_read_b128 fragment loads while
// keeping global_load_lds's fixed base+lane*16 mapping.
// ---------------------------------------------------------------------------
template <int KTOT, bool L0>
__global__ __launch_bounds__(256, 1) void gates_kernel(
    const bf16* __restrict__ A0,      // k in [0,1024)
    const bf16* __restrict__ A1,      // k in [1024,2048) (unused if KTOT==1024)
    const bf16* __restrict__ Wp,      // [3][1024][KTOT]
    const float* __restrict__ bias4,  // [4][1024]: r, z, in, hn biases
    const float* __restrict__ table,  // [100][3072] (L0 only)
    const float* __restrict__ gprec,  // [512][3072] (L0 only)
    const int* __restrict__ inputs,   // [512][200]  (L0 only)
    int t,
    const bf16* __restrict__ hprev,   // h_l(t-1) [512][1024]
    bf16* __restrict__ hout)          // h_l(t)   [512][1024]
{
  constexpr int KH = KTOT / 2;
  constexpr int NITER = KH / 64;
  __shared__ char smem[40960];  // A granules: 1024*16B, B granules: 1536*16B
  const int tid = threadIdx.x;
  const int lane = tid & 63;
  const int w = tid >> 6;
  const int wm = w & 1, ks = w >> 1;
  const int mb = blockIdx.x, nb = blockIdx.y;

  f32x16 accR, accZ, accN;
#pragma unroll
  for (int j = 0; j < 16; ++j) { accR[j] = 0.f; accZ[j] = 0.f; accN[j] = 0.f; }

  for (int it = 0; it < NITER; ++it) {
    const int kbase = it * 64;
    // ---- stage A (granules 0..1023) and B (1024..2559), 10 calls ----
#pragma unroll
    for (int c = 0; c < 10; ++c) {
      const int G = c * 256 + tid;
      const char* gp;
      if (G < 1024) {  // A granule: [ksA][row 0..63][kcs 0..7]
        int ksA = G >> 9, row = (G >> 3) & 63, kcs = G & 7;
        int kc = kcs ^ (row & 7);
        int k = ksA * KH + kbase + kc * 8;
        const bf16* src = (KTOT == 2048 && k >= 1024) ? A1 : A0;
        gp = (const char*)(src + ((mb * 64 + row) * H_ + (k & 1023)));
      } else {         // B granule: [g][ksB][nl 0..31][kcs 0..7]
        int Gb = G - 1024;
        int g = Gb >> 9, ksB = (Gb >> 8) & 1, nl = (Gb >> 3) & 31, kcs = Gb & 7;
        int kc = kcs ^ (nl & 7);
        int k = ksB * KH + kbase + kc * 8;
        gp = (const char*)(Wp + ((g * 1024 + nb * 32 + nl) * KTOT + k));
      }
      char* lp = smem + (c * 256 + w * 64) * 16;  // wave-uniform base
      __builtin_amdgcn_global_load_lds(
          (const __attribute__((address_space(1))) void*)gp,
          (__attribute__((address_space(3))) void*)lp, 16, 0, 0);
    }
    __syncthreads();
    // ---- compute: 4 ksteps of 16 over this 64-k slab of my K-half ----
#pragma unroll
    for (int kk = 0; kk < 4; ++kk) {
      const int rowA = wm * 32 + (lane & 31);
      const int kc = kk * 2 + (lane >> 5);
      short8 af = *(const short8*)(smem +
          (((ks * 64 + rowA) * 8) + (kc ^ (rowA & 7))) * 16);
      const int nl = lane & 31;
      const int kcs = kc ^ (nl & 7);
      short8 bR = *(const short8*)(smem + 16384 +
          ((((0 * 2 + ks) * 32 + nl) * 8) + kcs) * 16);
      short8 bZ = *(const short8*)(smem + 16384 +
          ((((1 * 2 + ks) * 32 + nl) * 8) + kcs) * 16);
      short8 bN = *(const short8*)(smem + 16384 +
          ((((2 * 2 + ks) * 32 + nl) * 8) + kcs) * 16);
      accR = __builtin_amdgcn_mfma_f32_32x32x16_bf16(af, bR, accR, 0, 0, 0);
      accZ = __builtin_amdgcn_mfma_f32_32x32x16_bf16(af, bZ, accZ, 0, 0, 0);
      accN = __builtin_amdgcn_mfma_f32_32x32x16_bf16(af, bN, accN, 0, 0, 0);
    }
    __syncthreads();
  }

  // ---- cross-wave (K-split) reduction through LDS ----
  float* red = (float*)smem;
  if (ks == 1) {
#pragma unroll
    for (int j = 0; j < 16; ++j) {
      red[((wm * 3 + 0) * 16 + j) * 64 + lane] = accR[j];
      red[((wm * 3 + 1) * 16 + j) * 64 + lane] = accZ[j];
      red[((wm * 3 + 2) * 16 + j) * 64 + lane] = accN[j];
    }
  }
  __syncthreads();
  if (ks == 0) {
    const int nloc = lane & 31;
    const int n = nb * 32 + nloc;
    const float br = bias4[n], bz = bias4[1024 + n];
    const float bin = bias4[2048 + n], bhn = bias4[3072 + n];
#pragma unroll
    for (int j = 0; j < 16; ++j) {
      // C/D layout (32x32): col = lane&31, row = 4*(lane>>5)+(j&3)+8*(j>>2)
      int mloc = 4 * (lane >> 5) + (j & 3) + 8 * (j >> 2);
      int b = mb * 64 + wm * 32 + mloc;
      float r1 = red[((wm * 3 + 0) * 16 + j) * 64 + lane];
      float z1 = red[((wm * 3 + 1) * 16 + j) * 64 + lane];
      float n1 = red[((wm * 3 + 2) * 16 + j) * 64 + lane];
      float rt = accR[j] + r1 + br;
      float zt = accZ[j] + z1 + bz;
      float hn, npre;
      if (L0) {
        int tok = (t == 0) ? 1 : inputs[b * S_ + (t - 1)];
        const float* tb = table + tok * 3072;
        const float* gpv = gprec + b * 3072;
        rt += tb[n] + gpv[n];
        zt += tb[1024 + n] + gpv[1024 + n];
        hn = accN[j] + n1 + bhn;            // both halves are whh
        npre = tb[2048 + n] + gpv[2048 + n];  // i_n from table (incl bih0)
      } else {
        hn = n1 + bhn;          // ks=1 half == whh part
        npre = accN[j] + bin;   // ks=0 half == wih part
      }
      float r = 1.f / (1.f + __expf(-rt));
      float z = 1.f / (1.f + __expf(-zt));
      float nn = npre + r * hn;
      float e2 = __expf(2.f * nn);
      float th = 1.f - 2.f / (e2 + 1.f);  // tanh, inf-safe
      float hp = bf2f(hprev[b * H_ + n]);
      float hv = (1.f - z) * th + z * hp;
      hout[b * H_ + n] = __float2bfloat16(hv);
    }
  }
}

// ---------------------------------------------------------------------------
// OUT kernel: logits[b,t,v] = h2(t)[b,:] . out_w[v,:1024] + logit_de[b,v]
// ---------------------------------------------------------------------------
__global__ __launch_bounds__(128) void out_kernel(
    const bf16* __restrict__ h2, const bf16* __restrict__ owTv,  // [100][1024]
    const float* __restrict__ logit_de, float* __restrict__ out, int t)
{
  __shared__ float hs[H_];
  const int b = blockIdx.x, tid = threadIdx.x;
  for (int k = tid; k < H_; k += 128) hs[k] = bf2f(h2[b * H_ + k]);
  __syncthreads();
  if (tid < V_) {
    float acc = logit_de[b * V_ + tid];
    const ushort8* row = (const ushort8*)(owTv + tid * H_);
#pragma unroll 4
    for (int k8 = 0; k8 < H_ / 8; ++k8) {
      ushort8 wv = row[k8];
#pragma unroll
      for (int i = 0; i < 8; ++i) acc += hs[k8 * 8 + i] * us2f(wv[i]);
    }
    out[(b * S_ + t) * V_ + tid] = acc;
  }
}

// ---------------------------------------------------------------------------
// fp32 precompute GEMM: C[m][n] = sum_k A[m*lda+k]*W[n*ldw+woff+k] + bias[n]
// ---------------------------------------------------------------------------
__global__ __launch_bounds__(256) void pgemm(
    const float* __restrict__ A, int lda, const float* __restrict__ W, int ldw,
    int woff, const float* __restrict__ bias, float* __restrict__ C,
    int M, int N, int K)
{
  __shared__ float As[64][33];
  __shared__ float Ws[64][33];
  const int tid = threadIdx.x;
  const int tx = tid & 15, ty = tid >> 4;
  const int mb = blockIdx.x * 64, nb = blockIdx.y * 64;
  float acc[4][4];
#pragma unroll
  for (int i = 0; i < 4; ++i)
#pragma unroll
    for (int j = 0; j < 4; ++j) acc[i][j] = 0.f;

  for (int k0 = 0; k0 < K; k0 += 32) {
#pragma unroll
    for (int s = 0; s < 8; ++s) {
      int idx = s * 256 + tid;
      int r = idx >> 5, c = idx & 31;
      int m = mb + r;
      As[r][c] = (m < M) ? A[m * lda + k0 + c] : 0.f;
      int n = nb + r;
      Ws[r][c] = (n < N) ? W[n * ldw + woff + k0 + c] : 0.f;
    }
    __syncthreads();
#pragma unroll 8
    for (int kk = 0; kk < 32; ++kk) {
      float a[4], ww[4];
#pragma unroll
      for (int i = 0; i < 4; ++i) a[i] = As[ty * 4 + i][kk];
#pragma unroll
      for (int j = 0; j < 4; ++j) ww[j] = Ws[tx * 4 + j][kk];
#pragma unroll
      for (int i = 0; i < 4; ++i)
#pragma unroll
        for (int j = 0; j < 4; ++j) acc[i][j] += a[i] * ww[j];
    }
    __syncthreads();
  }
#pragma unroll
  for (int i = 0; i < 4; ++i) {
    int m = mb + ty * 4 + i;
    if (m >= M) continue;
#pragma unroll
    for (int j = 0; j < 4; ++j) {
      int n = nb + tx * 4 + j;
      if (n < N) C[m * N + n] = acc[i][j] + (bias ? bias[n] : 0.f);
    }
  }
}

// --------------------------- small pack kernels ----------------------------
__global__ void k_de(const float* __restrict__ z, const float* __restrict__ c,
                     float* __restrict__ de) {
  int i = blockIdx.x * 256 + threadIdx.x;  // 512*1024
  int b = i >> 10, q = i & 1023;
  de[i] = (q < 512) ? z[b * 512 + q] : c[b * 512 + (q - 512)];
}

__global__ void k_wpack(const float* __restrict__ wih,
                        const float* __restrict__ whh, bf16* __restrict__ Wp,
                        int ktshift) {
  int KT = 1 << ktshift;
  int i = blockIdx.x * 256 + threadIdx.x;
  if (i >= 3072 * KT) return;
  int k = i & (KT - 1);
  int row = i >> ktshift;  // g*1024 + n
  float v = (k < 1024) ? wih[row * 1024 + k] : whh[row * 1024 + (k - 1024)];
  Wp[i] = __float2bfloat16(v);
}

__global__ void k_bias4(const float* __restrict__ bih,
                        const float* __restrict__ bhh, float* __restrict__ dst,
                        int l0) {
  int n = blockIdx.x * 256 + threadIdx.x;
  if (n >= 1024) return;
  dst[n] = l0 ? bhh[n] : bih[n] + bhh[n];
  dst[1024 + n] = l0 ? bhh[1024 + n] : bih[1024 + n] + bhh[1024 + n];
  dst[2048 + n] = l0 ? 0.f : bih[2048 + n];
  dst[3072 + n] = bhh[2048 + n];
}

__global__ void k_owt(const float* __restrict__ out_w, bf16* __restrict__ owTv) {
  int i = blockIdx.x * 256 + threadIdx.x;  // 100*1024
  if (i >= V_ * H_) return;
  int v = i >> 10, k = i & 1023;
  owTv[i] = __float2bfloat16(out_w[v * 2048 + k]);
}

__global__ void k_hinit(const float* __restrict__ hinit, bf16* __restrict__ h0,
                        bf16* __restrict__ h1, bf16* __restrict__ h2) {
  int i = blockIdx.x * 256 + threadIdx.x;  // 512*1024
  bf16 v = __float2bfloat16(hinit[i]);
  h0[i] = v; h1[i] = v; h2[i] = v;
}

// ---------------------------------------------------------------------------
extern "C" void kernel_launch(void* const* d_in, const int* in_sizes, int n_in,
                              void* d_out, int out_size, void* d_ws,
                              size_t ws_size, hipStream_t stream) {
  const int* inputs = (const int*)d_in[0];
  const float* z = (const float*)d_in[1];
  const float* cond = (const float*)d_in[2];
  // d_in[3] = temperature (ignored: >=1 -> always teacher-forced)
  const float* emb = (const float*)d_in[4];
  const float* i2h_w = (const float*)d_in[5];
  const float* i2h_b = (const float*)d_in[6];
  const float* out_w = (const float*)d_in[7];
  const float* out_b = (const float*)d_in[8];
  const float* wih0 = (const float*)d_in[9];
  const float* whh0 = (const float*)d_in[10];
  const float* bih0 = (const float*)d_in[11];
  const float* bhh0 = (const float*)d_in[12];
  const float* wih1 = (const float*)d_in[13];
  const float* whh1 = (const float*)d_in[14];
  const float* bih1 = (const float*)d_in[15];
  const float* bhh1 = (const float*)d_in[16];
  const float* wih2 = (const float*)d_in[17];
  const float* whh2 = (const float*)d_in[18];
  const float* bih2 = (const float*)d_in[19];
  const float* bhh2 = (const float*)d_in[20];
  float* out = (float*)d_out;

  char* p = (char*)d_ws;
  float* de = (float*)(p + 0);                 //  2 MB
  float* gprec0 = (float*)(p + 2097152);       //  6.29 MB
  float* table = (float*)(p + 8388608);        //  1.23 MB
  float* hinit = (float*)(p + 9617408);        //  2 MB
  float* logitde = (float*)(p + 11714560);     //  0.2 MB
  float* bias4 = (float*)(p + 11919360);       //  48 KB [3][4][1024]
  bf16* Wp0 = (bf16*)(p + 11968512);           //  6.29 MB
  bf16* Wp1 = (bf16*)(p + 18259968);           // 12.58 MB
  bf16* Wp2 = (bf16*)(p + 30842880);           // 12.58 MB
  bf16* owTv = (bf16*)(p + 43425792);          //  0.2 MB
  bf16* hbuf = (bf16*)(p + 43630592);          //  6.29 MB [2][3][512][1024]
#define HB(par, l) (hbuf + ((par) * 3 + (l)) * (B_ * H_))

  // ---- one-time precompute (per call; weights are re-restored each call) ----
  k_de<<<2048, 256, 0, stream>>>(z, cond, de);
  pgemm<<<dim3(8, 48), 256, 0, stream>>>(de, 1024, wih0, 1536, 512, bih0,
                                         gprec0, 512, 3072, 1024);
  pgemm<<<dim3(2, 48), 256, 0, stream>>>(emb, 512, wih0, 1536, 0, nullptr,
                                         table, 100, 3072, 512);
  pgemm<<<dim3(8, 16), 256, 0, stream>>>(de, 1024, i2h_w, 1024, 0, i2h_b,
                                         hinit, 512, 1024, 1024);
  pgemm<<<dim3(8, 2), 256, 0, stream>>>(de, 1024, out_w, 2048, 1024, out_b,
                                        logitde, 512, 100, 1024);
  k_bias4<<<4, 256, 0, stream>>>(bhh0, bhh0, bias4, 1);
  k_bias4<<<4, 256, 0, stream>>>(bih1, bhh1, bias4 + 4096, 0);
  k_bias4<<<4, 256, 0, stream>>>(bih2, bhh2, bias4 + 8192, 0);
  k_wpack<<<(3072 * 1024 + 255) / 256, 256, 0, stream>>>(whh0, whh0, Wp0, 10);
  k_wpack<<<(3072 * 2048 + 255) / 256, 256, 0, stream>>>(wih1, whh1, Wp1, 11);
  k_wpack<<<(3072 * 2048 + 255) / 256, 256, 0, stream>>>(wih2, whh2, Wp2, 11);
  k_owt<<<400, 256, 0, stream>>>(out_w, owTv);
  k_hinit<<<2048, 256, 0, stream>>>(hinit, HB(0, 0), HB(0, 1), HB(0, 2));

  // ---- sequential scan over S=200 steps ----
  const dim3 ggrid(8, 32);
  for (int t = 0; t < S_; ++t) {
    const int par = t & 1;
    bf16* h0p = HB(par, 0);
    bf16* h1p = HB(par, 1);
    bf16* h2p = HB(par, 2);
    bf16* h0n = HB(1 - par, 0);
    bf16* h1n = HB(1 - par, 1);
    bf16* h2n = HB(1 - par, 2);
    gates_kernel<1024, true><<<ggrid, 256, 0, stream>>>(
        h0p, h0p, Wp0, bias4, table, gprec0, inputs, t, h0p, h0n);
    gates_kernel<2048, false><<<ggrid, 256, 0, stream>>>(
        h0n, h1p, Wp1, bias4 + 4096, nullptr, nullptr, nullptr, t, h1p, h1n);
    gates_kernel<2048, false><<<ggrid, 256, 0, stream>>>(
        h1n, h2p, Wp2, bias4 + 8192, nullptr, nullptr, nullptr, t, h2p, h2n);
    out_kernel<<<512, 128, 0, stream>>>(h2n, owTv, logitde, out, t);
  }
#undef HB
}